// Round 11
// baseline (280.296 us; speedup 1.0000x reference)
//
#include <hip/hip_runtime.h>
#include <hip/hip_bf16.h>

typedef __hip_bfloat16 bf16;
typedef unsigned char u8;
typedef __attribute__((ext_vector_type(8))) __bf16 bf16x8;
typedef __attribute__((ext_vector_type(4))) float f32x4;

__device__ __forceinline__ void gld_lds16(const void* g, void* l) {
  __builtin_amdgcn_global_load_lds((const __attribute__((address_space(1))) void*)g,
                                   (__attribute__((address_space(3))) void*)l, 16, 0, 0);
}
__device__ __forceinline__ u8 f2e4m3(float v) {
  return (u8)(__builtin_amdgcn_cvt_pk_fp8_f32(v, 0.f, 0, false) & 0xff);
}

// ---------------- weight prep: fp32 -> bf16, transposed layouts (q,k,w1,w2) ----------------
__global__ __launch_bounds__(256) void prep_weights(
    const float* __restrict__ wq, const float* __restrict__ wk,
    const float* __restrict__ w1, const float* __restrict__ w2,
    bf16* __restrict__ WqkvT, bf16* __restrict__ w1T, bf16* __restrict__ w2T)
{
  int i = blockIdx.x * 256 + threadIdx.x;
  if (i < 221184) {                 // WqkvT[n][d], n: 0..575 q, 576..1151 k
    int n = i / 192, d = i % 192;
    int sel = n / 576, c = n % 576, h = c / 192, kd = c % 192;
    const float* w = (sel == 0) ? wq : wk;
    WqkvT[i] = __float2bfloat16(w[(d*3 + h)*192 + kd]);   // w[D][H][KD]
    return;
  }
  i -= 221184;
  if (i < 147456) {                 // w1T[j][d] = w1[d][j], w1 is [192][768]
    int j = i / 192, d = i % 192;
    w1T[i] = __float2bfloat16(w1[d*768 + j]);
    return;
  }
  i -= 147456;
  if (i < 147456) {                 // w2T[d][j] = w2[j][d], w2 is [768][192]
    int d = i / 768, j = i % 768;
    w2T[i] = __float2bfloat16(w2[j*192 + d]);
  }
}

// ---- Wm[(h,dd)][din] = sum_{g,kd} wv[din,(g,kd)] * post_w[h,g] * wo[(g,kd),dd] ----
__global__ __launch_bounds__(192) void wm_k(
    const float* __restrict__ wv, const float* __restrict__ wo,
    const float* __restrict__ post_w, bf16* __restrict__ WqkvT)
{
  const int dd = threadIdx.x;
  const int h  = blockIdx.x / 192;
  const int din = blockIdx.x % 192;
  float acc = 0.f;
  #pragma unroll
  for (int g2 = 0; g2 < 3; ++g2) {
    const float pw = post_w[h*3 + g2];
    const float* wvp = wv + (size_t)din*576 + g2*192;
    const float* wop = wo + (size_t)(g2*192)*192 + dd;
    float s = 0.f;
    for (int kd = 0; kd < 192; ++kd)
      s += wvp[kd] * wop[(size_t)kd*192];
    acc += pw * s;
  }
  WqkvT[(size_t)(1152 + h*192 + dd)*192 + din] = __float2bfloat16(acc);
}

// ---------------- LayerNorm (D=192): 1 wave per row, 4 rows/block ----------------
__global__ __launch_bounds__(256) void ln_k(const float* __restrict__ x,
    const float* __restrict__ gamma, const float* __restrict__ beta,
    bf16* __restrict__ out)
{
  int row = blockIdx.x * 4 + (threadIdx.x >> 6);
  int lane = threadIdx.x & 63;
  const float* xr = x + (size_t)row * 192;
  float v0 = xr[lane], v1 = xr[lane + 64], v2 = xr[lane + 128];
  float s = v0 + v1 + v2;
  #pragma unroll
  for (int o = 32; o; o >>= 1) s += __shfl_xor(s, o);
  float mu = s * (1.f / 192.f);
  float d0 = v0 - mu, d1 = v1 - mu, d2 = v2 - mu;
  float q = d0*d0 + d1*d1 + d2*d2;
  #pragma unroll
  for (int o = 32; o; o >>= 1) q += __shfl_xor(q, o);
  float rs = rsqrtf(q * (1.f / 192.f) + 1e-3f);
  bf16* orow = out + (size_t)row * 192;
  orow[lane]       = __float2bfloat16(d0*rs*gamma[lane]       + beta[lane]);
  orow[lane + 64]  = __float2bfloat16(d1*rs*gamma[lane + 64]  + beta[lane + 64]);
  orow[lane + 128] = __float2bfloat16(d2*rs*gamma[lane + 128] + beta[lane + 128]);
}

// ---------------- generic GEMM C = A[M,K] * BT[N,K]^T, 128x64 tile, 4 waves ----------------
enum { EPI_QKV = 0, EPI_GELU = 3, EPI_OUT = 4 };

template<int EPI>
__global__ __launch_bounds__(256) void gemm_bt(
    const bf16* __restrict__ A, const bf16* __restrict__ BT,
    int M, int N, int K,
    float* __restrict__ outF, bf16* __restrict__ outB,
    const float* __restrict__ bias,
    u8* __restrict__ q_out, u8* __restrict__ k_out, u8* __restrict__ mt_out)
{
  const int tid = threadIdx.x, lane = tid & 63, wid = tid >> 6;
  const int wm = wid >> 1, wn = wid & 1;
  const int row0 = blockIdx.y * 128, col0 = blockIdx.x * 64;
  __shared__ __align__(16) bf16 As[2][128 * 32];
  __shared__ __align__(16) bf16 Bs[2][64 * 32];
  f32x4 acc[4][2] = {};
  const int NT = K >> 5;

#define STAGE(buf_, kt_) do { \
    const bf16* Ab_ = A + (size_t)row0 * K + (kt_) * 32; \
    int c0_ = tid, r0_ = c0_ >> 2, cc0_ = (c0_ & 3) << 3; \
    gld_lds16(Ab_ + (size_t)r0_ * K + cc0_, &As[buf_][c0_ * 8]); \
    int c1_ = tid + 256, r1_ = c1_ >> 2, cc1_ = (c1_ & 3) << 3; \
    gld_lds16(Ab_ + (size_t)r1_ * K + cc1_, &As[buf_][c1_ * 8]); \
    const bf16* Bb_ = BT + (size_t)col0 * K + (kt_) * 32; \
    gld_lds16(Bb_ + (size_t)(tid >> 2) * K + ((tid & 3) << 3), &Bs[buf_][tid * 8]); \
  } while (0)

  STAGE(0, 0);
  for (int kt = 0; kt < NT; ++kt) {
    __syncthreads();
    const int buf = kt & 1;
    if (kt + 1 < NT) STAGE(buf ^ 1, kt + 1);
    const int koff = (lane >> 4) * 8;
    bf16x8 af[4], bfr[2];
    #pragma unroll
    for (int m = 0; m < 4; ++m)
      af[m] = *(const bf16x8*)&As[buf][(wm*64 + m*16 + (lane & 15))*32 + koff];
    #pragma unroll
    for (int n = 0; n < 2; ++n)
      bfr[n] = *(const bf16x8*)&Bs[buf][(wn*32 + n*16 + (lane & 15))*32 + koff];
    #pragma unroll
    for (int m = 0; m < 4; ++m)
      #pragma unroll
      for (int n = 0; n < 2; ++n)
        acc[m][n] = __builtin_amdgcn_mfma_f32_16x16x32_bf16(af[m], bfr[n], acc[m][n], 0, 0, 0);
  }
#undef STAGE

  const int rbase = row0 + wm * 64;
  const int cbase = col0 + wn * 32;
  #pragma unroll
  for (int m = 0; m < 4; ++m) {
    #pragma unroll
    for (int n = 0; n < 2; ++n) {
      const int col = cbase + n*16 + (lane & 15);
      const int rtop = rbase + m*16 + ((lane >> 4) << 2);
      if constexpr (EPI == EPI_QKV) {
        const int b = rtop >> 11, t_ = rtop & 2047;
        const int sel = col / 576, c2 = col % 576;
        const int h = c2 / 192, kd = c2 % 192;
        if (sel == 2) {
          int pk = __builtin_amdgcn_cvt_pk_fp8_f32(acc[m][n][0], acc[m][n][1], 0, false);
          pk = __builtin_amdgcn_cvt_pk_fp8_f32(acc[m][n][2], acc[m][n][3], pk, true);
          const size_t fo = ((((size_t)b*64 + (t_>>5))*3 + h)*12 + (kd>>4))*512
                          + (((kd&15) + (((t_>>3)&3)<<4))<<3) + (t_&4);
          *(unsigned*)&mt_out[fo] = (unsigned)pk;
        } else {
          #pragma unroll
          for (int j = 0; j < 4; ++j) {
            const int t = t_ + j;
            const size_t fo = ((((size_t)b*64 + (t>>5))*3 + h)*6 + (kd>>5))*1024
                            + (((t>>4)&1))*512
                            + (((t&15) + (((kd>>3)&3)<<4))<<3) + (kd&7);
            if (sel == 0) q_out[fo] = f2e4m3(acc[m][n][j]);
            else          k_out[fo] = f2e4m3(acc[m][n][j]);
          }
        }
      } else {
        #pragma unroll
        for (int j = 0; j < 4; ++j) {
          const int row = rtop + j;
          const float v = acc[m][n][j];
          if constexpr (EPI == EPI_GELU) {
            const float u = v + bias[col];
            outB[(size_t)row * 768 + col] =
                __float2bfloat16(0.5f * u * (1.f + erff(u * 0.70710678118654752f)));
          } else if constexpr (EPI == EPI_OUT) {
            const size_t idx = (size_t)row * 192 + col;
            outF[idx] = outF[idx] + v + bias[col];
          }
        }
      }
    }
  }
}

// ---------------- fused attention: 8 waves, t-tile 32, s-step 64, XCD-local ----------------
// QK role (tq=w&1, sq=w>>1 in 0..3): 16t x 16s; PV role (mq=w&1, dq=w>>1): 16t x 48d.
// Per step: [A: K staged, Ps[st-1] visible] QK mfma -> [B: Ks free] stageK(st+1) |
//           PV(st-1) (MT->reg per-g) | premix/exp/pack(st).
__global__ __launch_bounds__(512, 2) void attn_k(
    const u8* __restrict__ q, const u8* __restrict__ kf,
    const u8* __restrict__ MT, const float* __restrict__ pre_w,
    const float* __restrict__ x, float* __restrict__ out)
{
  const int tid = threadIdx.x, lane = tid & 63, w = tid >> 6;
  const int l15 = lane & 15, l4 = lane >> 4;
  const int tq = w & 1, sq = w >> 1;     // QK role
  const int mq = w & 1, dq = w >> 1;     // PV role
  const int bid = blockIdx.x;
  const int b = bid & 7;                 // XCD-local batch
  const int tt = bid >> 3;
  const int t0 = tt * 32;

  __shared__ __align__(16) u8 Ks[36864];        // [c(2)][h(3)][kq(6)][sh(2)][512]
  __shared__ __align__(16) u8 Ps[2][2][3][1024]; // [buf][half][g][t(32)*32B], R7 swizzle
  __shared__ float rlPart[4][3][32];

  // Q fragments resident (fragment-linear, coalesced one-time load)
  const u8* qfb = q + ((size_t)b*64 + tt) * 18432;
  long qf[18];
  #pragma unroll
  for (int hk = 0; hk < 18; ++hk)
    qf[hk] = *(const long*)(qfb + (hk*2 + tq)*512 + lane*8);

  // premix weights with 1/sqrt(192)*log2(e) folded
  float pwf[9];
  #pragma unroll
  for (int i = 0; i < 9; ++i) pwf[i] = pre_w[i] * 0.07216878364870323f * 1.44269504088896f;

  f32x4 acc[3][3] = {};
  float sgacc[3] = {0.f, 0.f, 0.f};
  const int trow = tq*16 + l15;                 // QK: t-row this lane packs
  const int prow = mq*16 + l15;                 // PV: t-row this lane reads
  const int psw = (l15 >> 2) & 3;
  const int half = sq >> 1, sqh = sq & 1;
  // R7-proven formulas (0 conflicts): write dword d = sqh*4+l4 at pair=(d>>1)^psw
  const int pwr = trow*32 + ((((sqh<<1) + (l4>>1)) ^ psw) << 3) + ((l4 & 1) << 2);
  const int prd = prow*32 + ((l4 ^ psw) << 3);
  const int kqb = (sq >> 1) * 18432 + (sq & 1) * 512 + lane*8;  // K-read base in Ks

  const u8* kfb = kf + (size_t)b * 64 * 18432;   // [st32][h][kq][sh][512]
  const u8* mtb = MT + (size_t)b * 64 * 18432 + (size_t)(dq*3)*512 + lane*8;

#define STAGEK(st_) do { \
    const u8* kb_ = kfb + (size_t)(st_) * 36864; \
    _Pragma("unroll") \
    for (int i_ = 0; i_ < 5; ++i_) { \
      const int L_ = i_ * 512 + tid; \
      if (L_ < 2304) gld_lds16(kb_ + L_*16, &Ks[L_*16]); \
    } \
  } while (0)

#define QKMM() do { \
    _Pragma("unroll") \
    for (int kq_ = 0; kq_ < 6; ++kq_) { \
      sacc0 = __builtin_amdgcn_mfma_f32_16x16x32_fp8_fp8( \
          *(const long*)&Ks[kqb + (0*6 + kq_)*1024], qf[kq_],      sacc0, 0, 0, 0); \
      sacc1 = __builtin_amdgcn_mfma_f32_16x16x32_fp8_fp8( \
          *(const long*)&Ks[kqb + (1*6 + kq_)*1024], qf[6 + kq_],  sacc1, 0, 0, 0); \
      sacc2 = __builtin_amdgcn_mfma_f32_16x16x32_fp8_fp8( \
          *(const long*)&Ks[kqb + (2*6 + kq_)*1024], qf[12 + kq_], sacc2, 0, 0, 0); \
    } \
  } while (0)

#define SMPACK(st_) do { \
    _Pragma("unroll") \
    for (int g_ = 0; g_ < 3; ++g_) { \
      float e0_ = exp2f(sacc0[0]*pwf[g_] + sacc1[0]*pwf[3+g_] + sacc2[0]*pwf[6+g_]); \
      float e1_ = exp2f(sacc0[1]*pwf[g_] + sacc1[1]*pwf[3+g_] + sacc2[1]*pwf[6+g_]); \
      float e2_ = exp2f(sacc0[2]*pwf[g_] + sacc1[2]*pwf[3+g_] + sacc2[2]*pwf[6+g_]); \
      float e3_ = exp2f(sacc0[3]*pwf[g_] + sacc1[3]*pwf[3+g_] + sacc2[3]*pwf[6+g_]); \
      sgacc[g_] += (e0_ + e1_) + (e2_ + e3_); \
      int pk_ = __builtin_amdgcn_cvt_pk_fp8_f32(e0_, e1_, 0, false); \
      pk_ = __builtin_amdgcn_cvt_pk_fp8_f32(e2_, e3_, pk_, true); \
      *(unsigned*)&Ps[(st_) & 1][half][g_][pwr] = (unsigned)pk_; \
    } \
  } while (0)

#define PVHALF(stm1_, c_) do { \
    const u8* mb_ = mtb + (size_t)(2*(stm1_) + (c_)) * 18432; \
    _Pragma("unroll") \
    for (int g_ = 0; g_ < 3; ++g_) { \
      long mf0_ = *(const long*)(mb_ + (g_*12 + 0)*512); \
      long mf1_ = *(const long*)(mb_ + (g_*12 + 1)*512); \
      long mf2_ = *(const long*)(mb_ + (g_*12 + 2)*512); \
      const long pf_ = *(const long*)&Ps[(stm1_) & 1][c_][g_][prd]; \
      acc[g_][0] = __builtin_amdgcn_mfma_f32_16x16x32_fp8_fp8(pf_, mf0_, acc[g_][0], 0, 0, 0); \
      acc[g_][1] = __builtin_amdgcn_mfma_f32_16x16x32_fp8_fp8(pf_, mf1_, acc[g_][1], 0, 0, 0); \
      acc[g_][2] = __builtin_amdgcn_mfma_f32_16x16x32_fp8_fp8(pf_, mf2_, acc[g_][2], 0, 0, 0); \
    } \
  } while (0)

  STAGEK(0);
  // ---- st = 0 (peeled: no PV) ----
  __syncthreads();
  {
    f32x4 sacc0 = {}, sacc1 = {}, sacc2 = {};
    QKMM();
    __syncthreads();
    STAGEK(1);
    SMPACK(0);
  }
  // ---- main loop ----
  for (int st = 1; st < 32; ++st) {
    __syncthreads();                    // A: K(st) staged, Ps[st-1] complete
    f32x4 sacc0 = {}, sacc1 = {}, sacc2 = {};
    QKMM();
    __syncthreads();                    // B: Ks consumed
    if (st < 31) STAGEK(st + 1);
    __builtin_amdgcn_s_setprio(1);
    PVHALF(st - 1, 0);
    PVHALF(st - 1, 1);
    __builtin_amdgcn_s_setprio(0);
    SMPACK(st);
  }
  // ---- final PV ----
  __syncthreads();
  PVHALF(31, 0);
  PVHALF(31, 1);

  // row-sum partials -> rl
  #pragma unroll
  for (int g = 0; g < 3; ++g) {
    float s = sgacc[g];
    s += __shfl_xor(s, 16);
    s += __shfl_xor(s, 32);
    if (l4 == 0) rlPart[sq][g][trow] = s;
  }
  __syncthreads();

  // epilogue: out = x + sum_g acc_g / L_g  (wave (dq,mq): rows mq*16.., d-slice dq*48)
  #pragma unroll
  for (int j = 0; j < 4; ++j) {
    const int row = mq*16 + l4*4 + j;
    float rlv[3];
    #pragma unroll
    for (int g = 0; g < 3; ++g)
      rlv[g] = 1.f / (rlPart[0][g][row] + rlPart[1][g][row] + rlPart[2][g][row] + rlPart[3][g][row]);
    #pragma unroll
    for (int n = 0; n < 3; ++n) {
      const int d = dq*48 + n*16 + l15;
      const size_t idx = ((size_t)b*2048 + t0 + row)*192 + d;
      out[idx] = x[idx] + rlv[0]*acc[0][n][j] + rlv[1]*acc[1][n][j] + rlv[2]*acc[2][n][j];
    }
  }
#undef STAGEK
#undef QKMM
#undef SMPACK
#undef PVHALF
}

// ---------------- host launcher ----------------
extern "C" void kernel_launch(void* const* d_in, const int* in_sizes, int n_in,
                              void* d_out, int out_size, void* d_ws, size_t ws_size,
                              hipStream_t stream)
{
  (void)in_sizes; (void)n_in; (void)out_size; (void)ws_size;
  const float* x      = (const float*)d_in[0];
  const float* gamma1 = (const float*)d_in[1];
  const float* beta1  = (const float*)d_in[2];
  const float* gamma2 = (const float*)d_in[3];
  const float* beta2  = (const float*)d_in[4];
  const float* wq     = (const float*)d_in[5];
  const float* wk     = (const float*)d_in[6];
  const float* wv     = (const float*)d_in[7];
  const float* wo     = (const float*)d_in[8];
  const float* pre_w  = (const float*)d_in[9];
  const float* post_w = (const float*)d_in[10];
  const float* w1     = (const float*)d_in[11];
  const float* b1     = (const float*)d_in[12];
  const float* w2     = (const float*)d_in[13];
  const float* b2     = (const float*)d_in[14];
  float* out = (float*)d_out;

  uint8_t* base = (uint8_t*)d_ws;
  size_t off = 0;
  auto alloc = [&](size_t bytes) {
    uint8_t* r = base + off; off += (bytes + 255) & ~(size_t)255; return r;
  };
  bf16* nb      = (bf16*)alloc((size_t)16384 * 192 * 2);    // n1 / n2
  u8*   qb      = (u8*)alloc((size_t)9437184);              // Q frag [b][tt][h][kq][th][512]
  u8*   kb      = (u8*)alloc((size_t)9437184);              // K frag [b][st][h][kq][sh][512]
  u8*   MTslab  = (u8*)alloc((size_t)9437184);              // MT frag [b][st][g][dn][512]
  bf16* WqkvT   = (bf16*)alloc((size_t)331776 * 2);         // rows 0..1151 q,k; 1152..1727 Wm
  bf16* w1T     = (bf16*)alloc((size_t)147456 * 2);
  bf16* w2T     = (bf16*)alloc((size_t)147456 * 2);
  bf16* hb      = (bf16*)qb;  // overlay: q/k/MT dead by MLP time

  prep_weights<<<2016, 256, 0, stream>>>(wq, wk, w1, w2, WqkvT, w1T, w2T);
  wm_k<<<576, 192, 0, stream>>>(wv, wo, post_w, WqkvT);
  ln_k<<<4096, 256, 0, stream>>>(x, gamma1, beta1, nb);
  gemm_bt<EPI_QKV><<<dim3(27, 128, 1), 256, 0, stream>>>(nb, WqkvT, 16384, 1728, 192,
      nullptr, nullptr, nullptr, qb, kb, MTslab);
  attn_k<<<512, 512, 0, stream>>>(qb, kb, MTslab, pre_w, x, out);
  ln_k<<<4096, 256, 0, stream>>>(out, gamma2, beta2, nb);
  gemm_bt<EPI_GELU><<<dim3(12, 128, 1), 256, 0, stream>>>(nb, w1T, 16384, 768, 192,
      nullptr, hb, b1, nullptr, nullptr, nullptr);
  gemm_bt<EPI_OUT><<<dim3(3, 128, 1), 256, 0, stream>>>(hb, w2T, 16384, 192, 768,
      out, nullptr, b2, nullptr, nullptr, nullptr);
}

// Round 12
// 197.595 us; speedup vs baseline: 1.4185x; 1.4185x over previous
//
#include <hip/hip_runtime.h>
#include <hip/hip_bf16.h>

typedef __hip_bfloat16 bf16;
typedef unsigned char u8;
typedef __attribute__((ext_vector_type(8))) __bf16 bf16x8;
typedef __attribute__((ext_vector_type(4))) float f32x4;

__device__ __forceinline__ void gld_lds16(const void* g, void* l) {
  __builtin_amdgcn_global_load_lds((const __attribute__((address_space(1))) void*)g,
                                   (__attribute__((address_space(3))) void*)l, 16, 0, 0);
}
__device__ __forceinline__ u8 f2e4m3(float v) {
  return (u8)(__builtin_amdgcn_cvt_pk_fp8_f32(v, 0.f, 0, false) & 0xff);
}

// ---------------- weight prep: fp32 -> bf16, transposed layouts (q,k,w1,w2) ----------------
__global__ __launch_bounds__(256) void prep_weights(
    const float* __restrict__ wq, const float* __restrict__ wk,
    const float* __restrict__ w1, const float* __restrict__ w2,
    bf16* __restrict__ WqkvT, bf16* __restrict__ w1T, bf16* __restrict__ w2T)
{
  int i = blockIdx.x * 256 + threadIdx.x;
  if (i < 221184) {                 // WqkvT[n][d], n: 0..575 q, 576..1151 k
    int n = i / 192, d = i % 192;
    int sel = n / 576, c = n % 576, h = c / 192, kd = c % 192;
    const float* w = (sel == 0) ? wq : wk;
    WqkvT[i] = __float2bfloat16(w[(d*3 + h)*192 + kd]);   // w[D][H][KD]
    return;
  }
  i -= 221184;
  if (i < 147456) {                 // w1T[j][d] = w1[d][j], w1 is [192][768]
    int j = i / 192, d = i % 192;
    w1T[i] = __float2bfloat16(w1[d*768 + j]);
    return;
  }
  i -= 147456;
  if (i < 147456) {                 // w2T[d][j] = w2[j][d], w2 is [768][192]
    int d = i / 768, j = i % 768;
    w2T[i] = __float2bfloat16(w2[j*192 + d]);
  }
}

// ---- Wm[(h,dd)][din] = sum_{g,kd} wv[din,(g,kd)] * post_w[h,g] * wo[(g,kd),dd] ----
// Written into WqkvT rows 1152..1727 (replaces the old v-projection columns).
__global__ __launch_bounds__(192) void wm_k(
    const float* __restrict__ wv, const float* __restrict__ wo,
    const float* __restrict__ post_w, bf16* __restrict__ WqkvT)
{
  const int dd = threadIdx.x;           // output d (0..191), coalesced over wo
  const int h  = blockIdx.x / 192;      // 0..2
  const int din = blockIdx.x % 192;     // input dim
  float acc = 0.f;
  #pragma unroll
  for (int g2 = 0; g2 < 3; ++g2) {
    const float pw = post_w[h*3 + g2];
    const float* wvp = wv + (size_t)din*576 + g2*192;   // wv[din,(g2,kd)], contiguous in kd
    const float* wop = wo + (size_t)(g2*192)*192 + dd;  // wo[(g2,kd),dd], stride 192
    float s = 0.f;
    for (int kd = 0; kd < 192; ++kd)
      s += wvp[kd] * wop[(size_t)kd*192];
    acc += pw * s;
  }
  WqkvT[(size_t)(1152 + h*192 + dd)*192 + din] = __float2bfloat16(acc);
}

// ---------------- LayerNorm (D=192): 1 wave per row, 4 rows/block ----------------
__global__ __launch_bounds__(256) void ln_k(const float* __restrict__ x,
    const float* __restrict__ gamma, const float* __restrict__ beta,
    bf16* __restrict__ out)
{
  int row = blockIdx.x * 4 + (threadIdx.x >> 6);
  int lane = threadIdx.x & 63;
  const float* xr = x + (size_t)row * 192;
  float v0 = xr[lane], v1 = xr[lane + 64], v2 = xr[lane + 128];
  float s = v0 + v1 + v2;
  #pragma unroll
  for (int o = 32; o; o >>= 1) s += __shfl_xor(s, o);
  float mu = s * (1.f / 192.f);
  float d0 = v0 - mu, d1 = v1 - mu, d2 = v2 - mu;
  float q = d0*d0 + d1*d1 + d2*d2;
  #pragma unroll
  for (int o = 32; o; o >>= 1) q += __shfl_xor(q, o);
  float rs = rsqrtf(q * (1.f / 192.f) + 1e-3f);
  bf16* orow = out + (size_t)row * 192;
  orow[lane]       = __float2bfloat16(d0*rs*gamma[lane]       + beta[lane]);
  orow[lane + 64]  = __float2bfloat16(d1*rs*gamma[lane + 64]  + beta[lane + 64]);
  orow[lane + 128] = __float2bfloat16(d2*rs*gamma[lane + 128] + beta[lane + 128]);
}

// ---------------- generic GEMM C = A[M,K] * BT[N,K]^T, 128x64 tile, 4 waves ----------------
enum { EPI_QKV = 0, EPI_GELU = 3, EPI_OUT = 4 };

template<int EPI>
__global__ __launch_bounds__(256) void gemm_bt(
    const bf16* __restrict__ A, const bf16* __restrict__ BT,
    int M, int N, int K,
    float* __restrict__ outF, bf16* __restrict__ outB,
    const float* __restrict__ bias,
    u8* __restrict__ q_out, u8* __restrict__ k_out, u8* __restrict__ mt_out)
{
  const int tid = threadIdx.x, lane = tid & 63, wid = tid >> 6;
  const int wm = wid >> 1, wn = wid & 1;
  const int row0 = blockIdx.y * 128, col0 = blockIdx.x * 64;
  __shared__ __align__(16) bf16 As[2][128 * 32];
  __shared__ __align__(16) bf16 Bs[2][64 * 32];
  f32x4 acc[4][2] = {};
  const int NT = K >> 5;

#define STAGE(buf_, kt_) do { \
    const bf16* Ab_ = A + (size_t)row0 * K + (kt_) * 32; \
    int c0_ = tid, r0_ = c0_ >> 2, cc0_ = (c0_ & 3) << 3; \
    gld_lds16(Ab_ + (size_t)r0_ * K + cc0_, &As[buf_][c0_ * 8]); \
    int c1_ = tid + 256, r1_ = c1_ >> 2, cc1_ = (c1_ & 3) << 3; \
    gld_lds16(Ab_ + (size_t)r1_ * K + cc1_, &As[buf_][c1_ * 8]); \
    const bf16* Bb_ = BT + (size_t)col0 * K + (kt_) * 32; \
    gld_lds16(Bb_ + (size_t)(tid >> 2) * K + ((tid & 3) << 3), &Bs[buf_][tid * 8]); \
  } while (0)

  STAGE(0, 0);
  for (int kt = 0; kt < NT; ++kt) {
    __syncthreads();
    const int buf = kt & 1;
    if (kt + 1 < NT) STAGE(buf ^ 1, kt + 1);
    const int koff = (lane >> 4) * 8;
    bf16x8 af[4], bfr[2];
    #pragma unroll
    for (int m = 0; m < 4; ++m)
      af[m] = *(const bf16x8*)&As[buf][(wm*64 + m*16 + (lane & 15))*32 + koff];
    #pragma unroll
    for (int n = 0; n < 2; ++n)
      bfr[n] = *(const bf16x8*)&Bs[buf][(wn*32 + n*16 + (lane & 15))*32 + koff];
    #pragma unroll
    for (int m = 0; m < 4; ++m)
      #pragma unroll
      for (int n = 0; n < 2; ++n)
        acc[m][n] = __builtin_amdgcn_mfma_f32_16x16x32_bf16(af[m], bfr[n], acc[m][n], 0, 0, 0);
  }
#undef STAGE

  const int rbase = row0 + wm * 64;
  const int cbase = col0 + wn * 32;
  #pragma unroll
  for (int m = 0; m < 4; ++m) {
    #pragma unroll
    for (int n = 0; n < 2; ++n) {
      const int col = cbase + n*16 + (lane & 15);
      const int rtop = rbase + m*16 + ((lane >> 4) << 2);
      if constexpr (EPI == EPI_QKV) {
        const int b = rtop >> 11, t_ = rtop & 2047;       // 128-tiles never straddle batches
        const int sel = col / 576, c2 = col % 576;        // block-uniform (576%64==0)
        const int h = c2 / 192, kd = c2 % 192;
        if (sel == 2) {
          // MT fragment store: [b][s>>5][g=h][dn=kd>>4][512]; 4 consecutive s -> one dword
          int pk = __builtin_amdgcn_cvt_pk_fp8_f32(acc[m][n][0], acc[m][n][1], 0, false);
          pk = __builtin_amdgcn_cvt_pk_fp8_f32(acc[m][n][2], acc[m][n][3], pk, true);
          const size_t fo = ((((size_t)b*64 + (t_>>5))*3 + h)*12 + (kd>>4))*512
                          + (((kd&15) + (((t_>>3)&3)<<4))<<3) + (t_&4);
          *(unsigned*)&mt_out[fo] = (unsigned)pk;
        } else {
          #pragma unroll
          for (int j = 0; j < 4; ++j) {
            const int t = t_ + j;
            // q,k fragment-linear: [b][t>>5][h][kq(6)][(t>>4)&1][512]
            const size_t fo = ((((size_t)b*64 + (t>>5))*3 + h)*6 + (kd>>5))*1024
                            + (((t>>4)&1))*512
                            + (((t&15) + (((kd>>3)&3)<<4))<<3) + (kd&7);
            if (sel == 0) q_out[fo] = f2e4m3(acc[m][n][j]);
            else          k_out[fo] = f2e4m3(acc[m][n][j]);
          }
        }
      } else {
        #pragma unroll
        for (int j = 0; j < 4; ++j) {
          const int row = rtop + j;
          const float v = acc[m][n][j];
          if constexpr (EPI == EPI_GELU) {
            const float u = v + bias[col];
            outB[(size_t)row * 768 + col] =
                __float2bfloat16(0.5f * u * (1.f + erff(u * 0.70710678118654752f)));
          } else if constexpr (EPI == EPI_OUT) {
            const size_t idx = (size_t)row * 192 + col;
            outF[idx] = outF[idx] + v + bias[col];
          }
        }
      }
    }
  }
}

// ---------------- fused attention (R9 structure + XCD-local mapping + setprio) ----------------
// Block: 32 t-rows of one batch, 4 waves. s-loop step 32, 1 barrier/step.
// step i: [barrier] stageK(i+1) | loadMT(i)->regs (one step ahead) | PV(i-1) | QK(i) | exp+pack
// XCD-local: b = bid&7 (consecutive blocks round-robin XCDs -> each XCD sees one batch).
__global__ __launch_bounds__(256, 2) void attn_k(
    const u8* __restrict__ q, const u8* __restrict__ kf,
    const u8* __restrict__ MT, const float* __restrict__ pre_w,
    const float* __restrict__ x, float* __restrict__ out)
{
  const int tid = threadIdx.x, lane = tid & 63, wv = tid >> 6;
  const int l15 = lane & 15, l4 = lane >> 4;
  const int tq = wv & 1, sq = wv >> 1;
  const int bid = blockIdx.x;
  const int b = bid & 7;                 // XCD-local batch
  const int tt = bid >> 3;
  const int t0 = tt * 32;

  // K tiles: [2 buf][18432] fragment-linear: [(h*6+kq)*2 + sh][512]
  __shared__ __align__(16) u8 Ks[2][18432];
  // P tiles: [2 buf][g][t(32)][32 fp8], dword-pair XOR-swizzled by (t>>2)&3
  __shared__ __align__(16) u8 Ps[2][3072];
  __shared__ float rlPart[2][3][32];

  // Q fragments resident (fragment-linear, coalesced one-time load)
  const u8* qfb = q + ((size_t)b*64 + tt) * 18432;
  long qf[3][6];
  #pragma unroll
  for (int h = 0; h < 3; ++h)
    #pragma unroll
    for (int kq = 0; kq < 6; ++kq)
      qf[h][kq] = *(const long*)(qfb + ((h*6 + kq)*2 + tq)*512 + lane*8);

  // premix weights with 1/sqrt(192)*log2(e) folded
  float pwf[9];
  #pragma unroll
  for (int i = 0; i < 9; ++i) pwf[i] = pre_w[i] * 0.07216878364870323f * 1.44269504088896f;

  f32x4 acc[3][2][3] = {};
  float sgacc[3] = {0.f, 0.f, 0.f};
  const int trow = tq*16 + l15;
  const int psw = (l15 >> 2) & 3;                                  // P swizzle key
  const int pwr = (((sq*2 + (l4 >> 1)) ^ psw) << 3) + ((l4 & 1) << 2);  // write byte off in row
  const int prd = (l4 ^ psw) << 3;                                 // read byte off in row

  const u8* kfb = kf + (size_t)b * 64 * 18432;   // [st][h][kq][sh][512]
  const u8* mtb = MT + (size_t)b * 64 * 18432;   // [st][g][dn(12)][512]

#define STAGEK(buf_, st_) do { \
    const u8* kb_ = kfb + (size_t)(st_) * 18432; \
    _Pragma("unroll") \
    for (int i_ = 0; i_ < 5; ++i_) { \
      const int L_ = i_ * 256 + tid; \
      if (L_ < 1152) gld_lds16(kb_ + L_*16, &Ks[buf_][L_*16]); \
    } \
  } while (0)

#define LOADMF(MF_, st_) do { \
    const u8* mb_ = mtb + (size_t)(st_) * 18432 + wv*3*512 + lane*8; \
    _Pragma("unroll") \
    for (int g_ = 0; g_ < 3; ++g_) \
      _Pragma("unroll") \
      for (int n_ = 0; n_ < 3; ++n_) \
        MF_[g_][n_] = *(const long*)(mb_ + (g_*12 + n_)*512); \
  } while (0)

#define PV(stm1_, MF_) do { \
    const int bp_ = (stm1_) & 1; \
    __builtin_amdgcn_s_setprio(1); \
    _Pragma("unroll") \
    for (int g_ = 0; g_ < 3; ++g_) \
      _Pragma("unroll") \
      for (int m_ = 0; m_ < 2; ++m_) { \
        const long pf_ = *(const long*)&Ps[bp_][g_*1024 + (m_*16 + l15)*32 + prd]; \
        _Pragma("unroll") \
        for (int n_ = 0; n_ < 3; ++n_) \
          acc[g_][m_][n_] = __builtin_amdgcn_mfma_f32_16x16x32_fp8_fp8(pf_, MF_[g_][n_], acc[g_][m_][n_], 0, 0, 0); \
      } \
    __builtin_amdgcn_s_setprio(0); \
  } while (0)

#define QKSM(st_) do { \
    const int bq_ = (st_) & 1; \
    f32x4 sacc0 = {}, sacc1 = {}, sacc2 = {}; \
    __builtin_amdgcn_s_setprio(1); \
    _Pragma("unroll") \
    for (int kq_ = 0; kq_ < 6; ++kq_) { \
      const long kf0_ = *(const long*)&Ks[bq_][((0*6 + kq_)*2 + sq)*512 + lane*8]; \
      sacc0 = __builtin_amdgcn_mfma_f32_16x16x32_fp8_fp8(kf0_, qf[0][kq_], sacc0, 0, 0, 0); \
      const long kf1_ = *(const long*)&Ks[bq_][((1*6 + kq_)*2 + sq)*512 + lane*8]; \
      sacc1 = __builtin_amdgcn_mfma_f32_16x16x32_fp8_fp8(kf1_, qf[1][kq_], sacc1, 0, 0, 0); \
      const long kf2_ = *(const long*)&Ks[bq_][((2*6 + kq_)*2 + sq)*512 + lane*8]; \
      sacc2 = __builtin_amdgcn_mfma_f32_16x16x32_fp8_fp8(kf2_, qf[2][kq_], sacc2, 0, 0, 0); \
    } \
    __builtin_amdgcn_s_setprio(0); \
    _Pragma("unroll") \
    for (int g_ = 0; g_ < 3; ++g_) { \
      float e0_ = exp2f(sacc0[0]*pwf[g_] + sacc1[0]*pwf[3+g_] + sacc2[0]*pwf[6+g_]); \
      float e1_ = exp2f(sacc0[1]*pwf[g_] + sacc1[1]*pwf[3+g_] + sacc2[1]*pwf[6+g_]); \
      float e2_ = exp2f(sacc0[2]*pwf[g_] + sacc1[2]*pwf[3+g_] + sacc2[2]*pwf[6+g_]); \
      float e3_ = exp2f(sacc0[3]*pwf[g_] + sacc1[3]*pwf[3+g_] + sacc2[3]*pwf[6+g_]); \
      sgacc[g_] += (e0_ + e1_) + (e2_ + e3_); \
      int pk_ = __builtin_amdgcn_cvt_pk_fp8_f32(e0_, e1_, 0, false); \
      pk_ = __builtin_amdgcn_cvt_pk_fp8_f32(e2_, e3_, pk_, true); \
      *(unsigned*)&Ps[bq_][g_*1024 + trow*32 + pwr] = (unsigned)pk_; \
    } \
  } while (0)

  long mfA[3][3], mfB[3][3];

  STAGEK(0, 0);
  // ---- st = 0 (peeled: no PV) ----
  __syncthreads();
  STAGEK(1, 1);
  LOADMF(mfA, 0);
  QKSM(0);
  // ---- main loop: steps 1..63 in pairs (odd = mfB, even = mfA) ----
  for (int st = 1; st < 63; st += 2) {
    __syncthreads();
    STAGEK((st + 1) & 1, st + 1);
    LOADMF(mfB, st);
    PV(st - 1, mfA);
    QKSM(st);
    __syncthreads();
    if (st + 2 < 64) STAGEK((st + 2) & 1, st + 2);
    LOADMF(mfA, st + 1);
    PV(st, mfB);
    QKSM(st + 1);
  }
  // ---- st = 63 (peeled: no stage) ----
  __syncthreads();
  LOADMF(mfB, 63);
  PV(62, mfA);
  QKSM(63);
  // ---- epilogue ----
  __syncthreads();
  PV(63, mfB);
  #pragma unroll
  for (int g = 0; g < 3; ++g) {
    float s = sgacc[g];
    s += __shfl_xor(s, 16);
    s += __shfl_xor(s, 32);
    if (l4 == 0) rlPart[sq][g][trow] = s;
  }
  __syncthreads();

  // out = x + sum_g rl_g * acc_g   (wave wv: d-slice wv*48)
  #pragma unroll
  for (int m = 0; m < 2; ++m) {
    #pragma unroll
    for (int j = 0; j < 4; ++j) {
      const int row = m*16 + l4*4 + j;
      float rlv[3];
      #pragma unroll
      for (int g = 0; g < 3; ++g)
        rlv[g] = 1.f / (rlPart[0][g][row] + rlPart[1][g][row]);
      #pragma unroll
      for (int n = 0; n < 3; ++n) {
        const int d = wv*48 + n*16 + l15;
        const size_t idx = ((size_t)b*2048 + t0 + row)*192 + d;
        out[idx] = x[idx] + rlv[0]*acc[0][m][n][j] + rlv[1]*acc[1][m][n][j]
                          + rlv[2]*acc[2][m][n][j];
      }
    }
  }
#undef STAGEK
#undef LOADMF
#undef PV
#undef QKSM
}

// ---------------- host launcher ----------------
extern "C" void kernel_launch(void* const* d_in, const int* in_sizes, int n_in,
                              void* d_out, int out_size, void* d_ws, size_t ws_size,
                              hipStream_t stream)
{
  (void)in_sizes; (void)n_in; (void)out_size; (void)ws_size;
  const float* x      = (const float*)d_in[0];
  const float* gamma1 = (const float*)d_in[1];
  const float* beta1  = (const float*)d_in[2];
  const float* gamma2 = (const float*)d_in[3];
  const float* beta2  = (const float*)d_in[4];
  const float* wq     = (const float*)d_in[5];
  const float* wk     = (const float*)d_in[6];
  const float* wv     = (const float*)d_in[7];
  const float* wo     = (const float*)d_in[8];
  const float* pre_w  = (const float*)d_in[9];
  const float* post_w = (const float*)d_in[10];
  const float* w1     = (const float*)d_in[11];
  const float* b1     = (const float*)d_in[12];
  const float* w2     = (const float*)d_in[13];
  const float* b2     = (const float*)d_in[14];
  float* out = (float*)d_out;

  uint8_t* base = (uint8_t*)d_ws;
  size_t off = 0;
  auto alloc = [&](size_t bytes) {
    uint8_t* r = base + off; off += (bytes + 255) & ~(size_t)255; return r;
  };
  bf16* nb      = (bf16*)alloc((size_t)16384 * 192 * 2);    // n1 / n2
  u8*   qb      = (u8*)alloc((size_t)9437184);              // Q frag [b][tt][h][kq][th][512]
  u8*   kb      = (u8*)alloc((size_t)9437184);              // K frag [b][st][h][kq][sh][512]
  u8*   MTslab  = (u8*)alloc((size_t)9437184);              // MT frag [b][st][g][dn][512]
  bf16* WqkvT   = (bf16*)alloc((size_t)331776 * 2);         // rows 0..1151 q,k; 1152..1727 Wm
  bf16* w1T     = (bf16*)alloc((size_t)147456 * 2);
  bf16* w2T     = (bf16*)alloc((size_t)147456 * 2);
  bf16* hb      = (bf16*)qb;  // overlay: q/k/MT dead by MLP time

  prep_weights<<<2016, 256, 0, stream>>>(wq, wk, w1, w2, WqkvT, w1T, w2T);
  wm_k<<<576, 192, 0, stream>>>(wv, wo, post_w, WqkvT);
  ln_k<<<4096, 256, 0, stream>>>(x, gamma1, beta1, nb);
  gemm_bt<EPI_QKV><<<dim3(27, 128, 1), 256, 0, stream>>>(nb, WqkvT, 16384, 1728, 192,
      nullptr, nullptr, nullptr, qb, kb, MTslab);
  attn_k<<<512, 256, 0, stream>>>(qb, kb, MTslab, pre_w, x, out);
  ln_k<<<4096, 256, 0, stream>>>(out, gamma2, beta2, nb);
  gemm_bt<EPI_GELU><<<dim3(12, 128, 1), 256, 0, stream>>>(nb, w1T, 16384, 768, 192,
      nullptr, hb, b1, nullptr, nullptr, nullptr);
  gemm_bt<EPI_OUT><<<dim3(3, 128, 1), 256, 0, stream>>>(hb, w2T, 16384, 192, 768,
      out, nullptr, b2, nullptr, nullptr, nullptr);
}

// Round 13
// 195.786 us; speedup vs baseline: 1.4316x; 1.0092x over previous
//
#include <hip/hip_runtime.h>
#include <hip/hip_bf16.h>

typedef __hip_bfloat16 bf16;
typedef unsigned char u8;
typedef __attribute__((ext_vector_type(8))) __bf16 bf16x8;
typedef __attribute__((ext_vector_type(4))) float f32x4;
typedef __attribute__((ext_vector_type(2))) float f32x2;

__device__ __forceinline__ void gld_lds16(const void* g, void* l) {
  __builtin_amdgcn_global_load_lds((const __attribute__((address_space(1))) void*)g,
                                   (__attribute__((address_space(3))) void*)l, 16, 0, 0);
}
__device__ __forceinline__ u8 f2e4m3(float v) {
  return (u8)(__builtin_amdgcn_cvt_pk_fp8_f32(v, 0.f, 0, false) & 0xff);
}
__device__ __forceinline__ f32x2 pk_mul(f32x2 a, f32x2 b) {
  f32x2 d;
  asm("v_pk_mul_f32 %0, %1, %2" : "=v"(d) : "v"(a), "v"(b));
  return d;
}
__device__ __forceinline__ f32x2 pk_fma(f32x2 a, f32x2 b, f32x2 c) {
  f32x2 d;
  asm("v_pk_fma_f32 %0, %1, %2, %3" : "=v"(d) : "v"(a), "v"(b), "v"(c));
  return d;
}

// ---------------- weight prep: fp32 -> bf16, transposed layouts (q,k,w1,w2) ----------------
__global__ __launch_bounds__(256) void prep_weights(
    const float* __restrict__ wq, const float* __restrict__ wk,
    const float* __restrict__ w1, const float* __restrict__ w2,
    bf16* __restrict__ WqkvT, bf16* __restrict__ w1T, bf16* __restrict__ w2T)
{
  int i = blockIdx.x * 256 + threadIdx.x;
  if (i < 221184) {                 // WqkvT[n][d], n: 0..575 q, 576..1151 k
    int n = i / 192, d = i % 192;
    int sel = n / 576, c = n % 576, h = c / 192, kd = c % 192;
    const float* w = (sel == 0) ? wq : wk;
    WqkvT[i] = __float2bfloat16(w[(d*3 + h)*192 + kd]);   // w[D][H][KD]
    return;
  }
  i -= 221184;
  if (i < 147456) {                 // w1T[j][d] = w1[d][j], w1 is [192][768]
    int j = i / 192, d = i % 192;
    w1T[i] = __float2bfloat16(w1[d*768 + j]);
    return;
  }
  i -= 147456;
  if (i < 147456) {                 // w2T[d][j] = w2[j][d], w2 is [768][192]
    int d = i / 768, j = i % 768;
    w2T[i] = __float2bfloat16(w2[j*192 + d]);
  }
}

// ---- Wm[(h,dd)][din] = sum_{g,kd} wv[din,(g,kd)] * post_w[h,g] * wo[(g,kd),dd] ----
__global__ __launch_bounds__(192) void wm_k(
    const float* __restrict__ wv, const float* __restrict__ wo,
    const float* __restrict__ post_w, bf16* __restrict__ WqkvT)
{
  const int dd = threadIdx.x;
  const int h  = blockIdx.x / 192;
  const int din = blockIdx.x % 192;
  float acc = 0.f;
  #pragma unroll
  for (int g2 = 0; g2 < 3; ++g2) {
    const float pw = post_w[h*3 + g2];
    const float* wvp = wv + (size_t)din*576 + g2*192;
    const float* wop = wo + (size_t)(g2*192)*192 + dd;
    float s = 0.f;
    for (int kd = 0; kd < 192; ++kd)
      s += wvp[kd] * wop[(size_t)kd*192];
    acc += pw * s;
  }
  WqkvT[(size_t)(1152 + h*192 + dd)*192 + din] = __float2bfloat16(acc);
}

// ---------------- LayerNorm (D=192): 1 wave per row, 4 rows/block ----------------
__global__ __launch_bounds__(256) void ln_k(const float* __restrict__ x,
    const float* __restrict__ gamma, const float* __restrict__ beta,
    bf16* __restrict__ out)
{
  int row = blockIdx.x * 4 + (threadIdx.x >> 6);
  int lane = threadIdx.x & 63;
  const float* xr = x + (size_t)row * 192;
  float v0 = xr[lane], v1 = xr[lane + 64], v2 = xr[lane + 128];
  float s = v0 + v1 + v2;
  #pragma unroll
  for (int o = 32; o; o >>= 1) s += __shfl_xor(s, o);
  float mu = s * (1.f / 192.f);
  float d0 = v0 - mu, d1 = v1 - mu, d2 = v2 - mu;
  float q = d0*d0 + d1*d1 + d2*d2;
  #pragma unroll
  for (int o = 32; o; o >>= 1) q += __shfl_xor(q, o);
  float rs = rsqrtf(q * (1.f / 192.f) + 1e-3f);
  bf16* orow = out + (size_t)row * 192;
  orow[lane]       = __float2bfloat16(d0*rs*gamma[lane]       + beta[lane]);
  orow[lane + 64]  = __float2bfloat16(d1*rs*gamma[lane + 64]  + beta[lane + 64]);
  orow[lane + 128] = __float2bfloat16(d2*rs*gamma[lane + 128] + beta[lane + 128]);
}

// ---------------- generic GEMM C = A[M,K] * BT[N,K]^T, MROWSx64 tile, 4 waves ----------------
enum { EPI_QKV = 0, EPI_GELU = 3, EPI_OUT = 4 };

template<int EPI, int MROWS = 128>
__global__ __launch_bounds__(256) void gemm_bt(
    const bf16* __restrict__ A, const bf16* __restrict__ BT,
    int M, int N, int K,
    float* __restrict__ outF, bf16* __restrict__ outB,
    const float* __restrict__ bias,
    u8* __restrict__ q_out, u8* __restrict__ k_out, u8* __restrict__ mt_out)
{
  constexpr int MB = MROWS / 32;
  const int tid = threadIdx.x, lane = tid & 63, wid = tid >> 6;
  const int wm = wid >> 1, wn = wid & 1;
  const int row0 = blockIdx.y * MROWS, col0 = blockIdx.x * 64;
  __shared__ __align__(16) bf16 As[2][MROWS * 32];
  __shared__ __align__(16) bf16 Bs[2][64 * 32];
  f32x4 acc[MB][2] = {};
  const int NT = K >> 5;

#define STAGE(buf_, kt_) do { \
    const bf16* Ab_ = A + (size_t)row0 * K + (kt_) * 32; \
    int c0_ = tid, r0_ = c0_ >> 2, cc0_ = (c0_ & 3) << 3; \
    gld_lds16(Ab_ + (size_t)r0_ * K + cc0_, &As[buf_][c0_ * 8]); \
    if constexpr (MROWS == 128) { \
      int c1_ = tid + 256, r1_ = c1_ >> 2, cc1_ = (c1_ & 3) << 3; \
      gld_lds16(Ab_ + (size_t)r1_ * K + cc1_, &As[buf_][c1_ * 8]); \
    } \
    const bf16* Bb_ = BT + (size_t)col0 * K + (kt_) * 32; \
    gld_lds16(Bb_ + (size_t)(tid >> 2) * K + ((tid & 3) << 3), &Bs[buf_][tid * 8]); \
  } while (0)

  STAGE(0, 0);
  for (int kt = 0; kt < NT; ++kt) {
    __syncthreads();
    const int buf = kt & 1;
    if (kt + 1 < NT) STAGE(buf ^ 1, kt + 1);
    const int koff = (lane >> 4) * 8;
    bf16x8 af[MB], bfr[2];
    #pragma unroll
    for (int m = 0; m < MB; ++m)
      af[m] = *(const bf16x8*)&As[buf][(wm*(MROWS/2) + m*16 + (lane & 15))*32 + koff];
    #pragma unroll
    for (int n = 0; n < 2; ++n)
      bfr[n] = *(const bf16x8*)&Bs[buf][(wn*32 + n*16 + (lane & 15))*32 + koff];
    #pragma unroll
    for (int m = 0; m < MB; ++m)
      #pragma unroll
      for (int n = 0; n < 2; ++n)
        acc[m][n] = __builtin_amdgcn_mfma_f32_16x16x32_bf16(af[m], bfr[n], acc[m][n], 0, 0, 0);
  }
#undef STAGE

  const int rbase = row0 + wm * (MROWS/2);
  const int cbase = col0 + wn * 32;
  #pragma unroll
  for (int m = 0; m < MB; ++m) {
    #pragma unroll
    for (int n = 0; n < 2; ++n) {
      const int col = cbase + n*16 + (lane & 15);
      const int rtop = rbase + m*16 + ((lane >> 4) << 2);
      if constexpr (EPI == EPI_QKV) {
        const int b = rtop >> 11, t_ = rtop & 2047;       // 128-tiles never straddle batches
        const int sel = col / 576, c2 = col % 576;        // block-uniform (576%64==0)
        const int h = c2 / 192, kd = c2 % 192;
        if (sel == 2) {
          // MT fragment store: [b][s>>5][g=h][dn=kd>>4][512]; 4 consecutive s -> one dword
          int pk = __builtin_amdgcn_cvt_pk_fp8_f32(acc[m][n][0], acc[m][n][1], 0, false);
          pk = __builtin_amdgcn_cvt_pk_fp8_f32(acc[m][n][2], acc[m][n][3], pk, true);
          const size_t fo = ((((size_t)b*64 + (t_>>5))*3 + h)*12 + (kd>>4))*512
                          + (((kd&15) + (((t_>>3)&3)<<4))<<3) + (t_&4);
          *(unsigned*)&mt_out[fo] = (unsigned)pk;
        } else {
          #pragma unroll
          for (int j = 0; j < 4; ++j) {
            const int t = t_ + j;
            // q,k fragment-linear: [b][t>>5][h][kq(6)][(t>>4)&1][512]
            const size_t fo = ((((size_t)b*64 + (t>>5))*3 + h)*6 + (kd>>5))*1024
                            + (((t>>4)&1))*512
                            + (((t&15) + (((kd>>3)&3)<<4))<<3) + (kd&7);
            if (sel == 0) q_out[fo] = f2e4m3(acc[m][n][j]);
            else          k_out[fo] = f2e4m3(acc[m][n][j]);
          }
        }
      } else {
        #pragma unroll
        for (int j = 0; j < 4; ++j) {
          const int row = rtop + j;
          const float v = acc[m][n][j];
          if constexpr (EPI == EPI_GELU) {
            const float u = v + bias[col];
            outB[(size_t)row * 768 + col] =
                __float2bfloat16(0.5f * u * (1.f + erff(u * 0.70710678118654752f)));
          } else if constexpr (EPI == EPI_OUT) {
            const size_t idx = (size_t)row * 192 + col;
            outF[idx] = outF[idx] + v + bias[col];
          }
        }
      }
    }
  }
}

// ---------------- fused attention + LN2 (R12 structure + pk_fma premix) ----------------
// Block: 32 t-rows of one batch, 4 waves. s-loop step 32, 1 barrier/step.
// step i: [barrier] stageK(i+1) | loadMT(i)->regs | PV(i-1) | QK(i) | pk-premix+exp+pack
// Epilogue: out = x + sum_g acc_g/L_g, then fused LayerNorm2 -> nb (bf16).
__global__ __launch_bounds__(256, 2) void attn_k(
    const u8* __restrict__ q, const u8* __restrict__ kf,
    const u8* __restrict__ MT, const float* __restrict__ pre_w,
    const float* __restrict__ x, const float* __restrict__ gamma2,
    const float* __restrict__ beta2, float* __restrict__ out,
    bf16* __restrict__ nb)
{
  const int tid = threadIdx.x, lane = tid & 63, wv = tid >> 6;
  const int l15 = lane & 15, l4 = lane >> 4;
  const int tq = wv & 1, sq = wv >> 1;
  const int bid = blockIdx.x;
  const int b = bid & 7;                 // XCD-local batch
  const int tt = bid >> 3;
  const int t0 = tt * 32;

  __shared__ __align__(16) u8 Ks[2][18432];   // K frag tiles
  __shared__ __align__(16) u8 Ps[2][3072];    // P tiles, dword-pair XOR swizzle
  __shared__ float rlPart[2][3][32];
  __shared__ float lnS[4][32][2];             // per-wave LN partials {sum, sumsq}

  // Q fragments resident (fragment-linear, coalesced one-time load)
  const u8* qfb = q + ((size_t)b*64 + tt) * 18432;
  long qf[3][6];
  #pragma unroll
  for (int h = 0; h < 3; ++h)
    #pragma unroll
    for (int kq = 0; kq < 6; ++kq)
      qf[h][kq] = *(const long*)(qfb + ((h*6 + kq)*2 + tq)*512 + lane*8);

  // premix weights with 1/sqrt(192)*log2(e) folded, splat into f32 pairs for pk math
  f32x2 pwf2[9];
  #pragma unroll
  for (int i = 0; i < 9; ++i) {
    const float v = pre_w[i] * 0.07216878364870323f * 1.44269504088896f;
    pwf2[i][0] = v; pwf2[i][1] = v;
  }

  f32x4 acc[3][2][3] = {};
  float sgacc[3] = {0.f, 0.f, 0.f};
  const int trow = tq*16 + l15;
  const int psw = (l15 >> 2) & 3;
  const int pwr = (((sq*2 + (l4 >> 1)) ^ psw) << 3) + ((l4 & 1) << 2);
  const int prd = (l4 ^ psw) << 3;

  const u8* kfb = kf + (size_t)b * 64 * 18432;
  const u8* mtb = MT + (size_t)b * 64 * 18432;

#define STAGEK(buf_, st_) do { \
    const u8* kb_ = kfb + (size_t)(st_) * 18432; \
    _Pragma("unroll") \
    for (int i_ = 0; i_ < 5; ++i_) { \
      const int L_ = i_ * 256 + tid; \
      if (L_ < 1152) gld_lds16(kb_ + L_*16, &Ks[buf_][L_*16]); \
    } \
  } while (0)

#define LOADMF(MF_, st_) do { \
    const u8* mb_ = mtb + (size_t)(st_) * 18432 + wv*3*512 + lane*8; \
    _Pragma("unroll") \
    for (int g_ = 0; g_ < 3; ++g_) \
      _Pragma("unroll") \
      for (int n_ = 0; n_ < 3; ++n_) \
        MF_[g_][n_] = *(const long*)(mb_ + (g_*12 + n_)*512); \
  } while (0)

#define PV(stm1_, MF_) do { \
    const int bp_ = (stm1_) & 1; \
    __builtin_amdgcn_s_setprio(1); \
    _Pragma("unroll") \
    for (int g_ = 0; g_ < 3; ++g_) \
      _Pragma("unroll") \
      for (int m_ = 0; m_ < 2; ++m_) { \
        const long pf_ = *(const long*)&Ps[bp_][g_*1024 + (m_*16 + l15)*32 + prd]; \
        _Pragma("unroll") \
        for (int n_ = 0; n_ < 3; ++n_) \
          acc[g_][m_][n_] = __builtin_amdgcn_mfma_f32_16x16x32_fp8_fp8(pf_, MF_[g_][n_], acc[g_][m_][n_], 0, 0, 0); \
      } \
    __builtin_amdgcn_s_setprio(0); \
  } while (0)

#define QKSM(st_) do { \
    const int bq_ = (st_) & 1; \
    f32x4 sacc0 = {}, sacc1 = {}, sacc2 = {}; \
    __builtin_amdgcn_s_setprio(1); \
    _Pragma("unroll") \
    for (int kq_ = 0; kq_ < 6; ++kq_) { \
      const long kf0_ = *(const long*)&Ks[bq_][((0*6 + kq_)*2 + sq)*512 + lane*8]; \
      sacc0 = __builtin_amdgcn_mfma_f32_16x16x32_fp8_fp8(kf0_, qf[0][kq_], sacc0, 0, 0, 0); \
      const long kf1_ = *(const long*)&Ks[bq_][((1*6 + kq_)*2 + sq)*512 + lane*8]; \
      sacc1 = __builtin_amdgcn_mfma_f32_16x16x32_fp8_fp8(kf1_, qf[1][kq_], sacc1, 0, 0, 0); \
      const long kf2_ = *(const long*)&Ks[bq_][((2*6 + kq_)*2 + sq)*512 + lane*8]; \
      sacc2 = __builtin_amdgcn_mfma_f32_16x16x32_fp8_fp8(kf2_, qf[2][kq_], sacc2, 0, 0, 0); \
    } \
    __builtin_amdgcn_s_setprio(0); \
    f32x2 p0a = {sacc0[0], sacc0[1]}, p0b = {sacc0[2], sacc0[3]}; \
    f32x2 p1a = {sacc1[0], sacc1[1]}, p1b = {sacc1[2], sacc1[3]}; \
    f32x2 p2a = {sacc2[0], sacc2[1]}, p2b = {sacc2[2], sacc2[3]}; \
    _Pragma("unroll") \
    for (int g_ = 0; g_ < 3; ++g_) { \
      f32x2 va = pk_mul(p0a, pwf2[g_]); \
      va = pk_fma(p1a, pwf2[3+g_], va); \
      va = pk_fma(p2a, pwf2[6+g_], va); \
      f32x2 vb = pk_mul(p0b, pwf2[g_]); \
      vb = pk_fma(p1b, pwf2[3+g_], vb); \
      vb = pk_fma(p2b, pwf2[6+g_], vb); \
      float e0_ = exp2f(va[0]), e1_ = exp2f(va[1]); \
      float e2_ = exp2f(vb[0]), e3_ = exp2f(vb[1]); \
      sgacc[g_] += (e0_ + e1_) + (e2_ + e3_); \
      int pk_ = __builtin_amdgcn_cvt_pk_fp8_f32(e0_, e1_, 0, false); \
      pk_ = __builtin_amdgcn_cvt_pk_fp8_f32(e2_, e3_, pk_, true); \
      *(unsigned*)&Ps[bq_][g_*1024 + trow*32 + pwr] = (unsigned)pk_; \
    } \
  } while (0)

  long mfA[3][3], mfB[3][3];

  STAGEK(0, 0);
  // ---- st = 0 (peeled: no PV) ----
  __syncthreads();
  STAGEK(1, 1);
  LOADMF(mfA, 0);
  QKSM(0);
  // ---- main loop: steps 1..63 in pairs (odd = mfB, even = mfA) ----
  for (int st = 1; st < 63; st += 2) {
    __syncthreads();
    STAGEK((st + 1) & 1, st + 1);
    LOADMF(mfB, st);
    PV(st - 1, mfA);
    QKSM(st);
    __syncthreads();
    if (st + 2 < 64) STAGEK((st + 2) & 1, st + 2);
    LOADMF(mfA, st + 1);
    PV(st, mfB);
    QKSM(st + 1);
  }
  // ---- st = 63 (peeled: no stage) ----
  __syncthreads();
  LOADMF(mfB, 63);
  PV(62, mfA);
  QKSM(63);
  // ---- epilogue ----
  __syncthreads();
  PV(63, mfB);
  #pragma unroll
  for (int g = 0; g < 3; ++g) {
    float s = sgacc[g];
    s += __shfl_xor(s, 16);
    s += __shfl_xor(s, 32);
    if (l4 == 0) rlPart[sq][g][trow] = s;
  }
  __syncthreads();

  // out = x + sum_g rl_g * acc_g, with LN partials (wave wv: d-slice wv*48)
  float ovv[2][3][4];
  #pragma unroll
  for (int m = 0; m < 2; ++m) {
    #pragma unroll
    for (int j = 0; j < 4; ++j) {
      const int row = m*16 + l4*4 + j;
      float rlv[3];
      #pragma unroll
      for (int g = 0; g < 3; ++g)
        rlv[g] = 1.f / (rlPart[0][g][row] + rlPart[1][g][row]);
      float s = 0.f, ss = 0.f;
      #pragma unroll
      for (int n = 0; n < 3; ++n) {
        const int d = wv*48 + n*16 + l15;
        const size_t idx = ((size_t)b*2048 + t0 + row)*192 + d;
        const float ov = x[idx] + rlv[0]*acc[0][m][n][j] + rlv[1]*acc[1][m][n][j]
                                + rlv[2]*acc[2][m][n][j];
        out[idx] = ov;
        ovv[m][n][j] = ov;
        s += ov; ss += ov*ov;
      }
      // reduce over the 16-lane (l15) group -> this wave's 48-d partial for row
      #pragma unroll
      for (int o = 1; o < 16; o <<= 1) { s += __shfl_xor(s, o); ss += __shfl_xor(ss, o); }
      if (l15 == 0) { lnS[wv][row][0] = s; lnS[wv][row][1] = ss; }
    }
  }
  __syncthreads();

  // fused LayerNorm2 -> nb
  float gmL[3], btL[3];
  #pragma unroll
  for (int n = 0; n < 3; ++n) {
    const int d = wv*48 + n*16 + l15;
    gmL[n] = gamma2[d]; btL[n] = beta2[d];
  }
  #pragma unroll
  for (int m = 0; m < 2; ++m) {
    #pragma unroll
    for (int j = 0; j < 4; ++j) {
      const int row = m*16 + l4*4 + j;
      const float ts  = lnS[0][row][0] + lnS[1][row][0] + lnS[2][row][0] + lnS[3][row][0];
      const float tss = lnS[0][row][1] + lnS[1][row][1] + lnS[2][row][1] + lnS[3][row][1];
      const float mu = ts * (1.f / 192.f);
      const float rs = rsqrtf(tss * (1.f / 192.f) - mu*mu + 1e-3f);
      #pragma unroll
      for (int n = 0; n < 3; ++n) {
        const int d = wv*48 + n*16 + l15;
        nb[((size_t)b*2048 + t0 + row)*192 + d] =
            __float2bfloat16((ovv[m][n][j] - mu) * rs * gmL[n] + btL[n]);
      }
    }
  }
#undef STAGEK
#undef LOADMF
#undef PV
#undef QKSM
}

// ---------------- host launcher ----------------
extern "C" void kernel_launch(void* const* d_in, const int* in_sizes, int n_in,
                              void* d_out, int out_size, void* d_ws, size_t ws_size,
                              hipStream_t stream)
{
  (void)in_sizes; (void)n_in; (void)out_size; (void)ws_size;
  const float* x      = (const float*)d_in[0];
  const float* gamma1 = (const float*)d_in[1];
  const float* beta1  = (const float*)d_in[2];
  const float* gamma2 = (const float*)d_in[3];
  const float* beta2  = (const float*)d_in[4];
  const float* wq     = (const float*)d_in[5];
  const float* wk     = (const float*)d_in[6];
  const float* wv     = (const float*)d_in[7];
  const float* wo     = (const float*)d_in[8];
  const float* pre_w  = (const float*)d_in[9];
  const float* post_w = (const float*)d_in[10];
  const float* w1     = (const float*)d_in[11];
  const float* b1     = (const float*)d_in[12];
  const float* w2     = (const float*)d_in[13];
  const float* b2     = (const float*)d_in[14];
  float* out = (float*)d_out;

  uint8_t* base = (uint8_t*)d_ws;
  size_t off = 0;
  auto alloc = [&](size_t bytes) {
    uint8_t* r = base + off; off += (bytes + 255) & ~(size_t)255; return r;
  };
  bf16* nb      = (bf16*)alloc((size_t)16384 * 192 * 2);    // n1 / n2
  u8*   qb      = (u8*)alloc((size_t)9437184);              // Q frag [b][tt][h][kq][th][512]
  u8*   kb      = (u8*)alloc((size_t)9437184);              // K frag [b][st][h][kq][sh][512]
  u8*   MTslab  = (u8*)alloc((size_t)9437184);              // MT frag [b][st][g][dn][512]
  bf16* WqkvT   = (bf16*)alloc((size_t)331776 * 2);         // rows 0..1151 q,k; 1152..1727 Wm
  bf16* w1T     = (bf16*)alloc((size_t)147456 * 2);
  bf16* w2T     = (bf16*)alloc((size_t)147456 * 2);
  bf16* hb      = (bf16*)qb;  // overlay: q/k/MT dead by MLP time

  prep_weights<<<2016, 256, 0, stream>>>(wq, wk, w1, w2, WqkvT, w1T, w2T);
  wm_k<<<576, 192, 0, stream>>>(wv, wo, post_w, WqkvT);
  ln_k<<<4096, 256, 0, stream>>>(x, gamma1, beta1, nb);
  gemm_bt<EPI_QKV, 128><<<dim3(27, 128, 1), 256, 0, stream>>>(nb, WqkvT, 16384, 1728, 192,
      nullptr, nullptr, nullptr, qb, kb, MTslab);
  attn_k<<<512, 256, 0, stream>>>(qb, kb, MTslab, pre_w, x, gamma2, beta2, out, nb);
  gemm_bt<EPI_GELU, 128><<<dim3(12, 128, 1), 256, 0, stream>>>(nb, w1T, 16384, 768, 192,
      nullptr, hb, b1, nullptr, nullptr, nullptr);
  gemm_bt<EPI_OUT, 64><<<dim3(3, 256, 1), 256, 0, stream>>>(hb, w2T, 16384, 192, 768,
      out, nullptr, b2, nullptr, nullptr, nullptr);
}